// Round 1
// baseline (456.447 us; speedup 1.0000x reference)
//
#include <hip/hip_runtime.h>

// HingeRankLoss on MI355X.
// B=32768 rows, L=2048 cols. scores fp32, candidate_lengths int32, labels int32
// (harness converts all integer inputs to int32). Output: single fp32 scalar.
//
// Only the valid prefix (j < len) of each row matters for both pos and neg
// masks, so we read only that prefix: ~halves HBM traffic vs full rows.
// One 256-thread block per row, 8 elements/thread held in registers across
// both phases (pos-score reduction, then hinge sum) -> single global read.

constexpr int L_DIM = 2048;
constexpr float MARGIN = 0.1f;
constexpr int NBUCKET = 1024;  // spread-atomic accumulator buckets in d_ws

__global__ __launch_bounds__(256) void hinge_row_kernel(
    const float* __restrict__ scores,
    const int*   __restrict__ lens,
    const int*   __restrict__ labels,
    float* __restrict__ acc_sum,   // [NBUCKET]
    float* __restrict__ acc_cnt)   // [NBUCKET]
{
    const int row = blockIdx.x;
    int len = lens[row];
    if (len <= 0) return;              // uniform per block: no barrier hazard
    if (len > L_DIM) len = L_DIM;

    const int t = threadIdx.x;
    const size_t base = (size_t)row * L_DIM;
    const float4* s4 = reinterpret_cast<const float4*>(scores + base);
    const int4*   l4 = reinterpret_cast<const int4*>(labels + base);

    float sc[8];                 // kept in registers between phases
    unsigned negmask = 0;
    float pos_local = 0.f;
    float haspos_local = 0.f;

    #pragma unroll
    for (int k = 0; k < 2; ++k) {
        const int v = t + k * 256;     // float4 index within row, 0..511
        const int j = v * 4;
        if (j < len) {
            const float4 sv = s4[v];
            const int4   lv = l4[v];
            const float se[4] = {sv.x, sv.y, sv.z, sv.w};
            const int    le[4] = {lv.x, lv.y, lv.z, lv.w};
            #pragma unroll
            for (int e = 0; e < 4; ++e) {
                const int jj = j + e;
                if (jj < len) {
                    if (le[e] == 1) { pos_local += se[e]; haspos_local = 1.f; }
                    else            { sc[k * 4 + e] = se[e];
                                      negmask |= 1u << (k * 4 + e); }
                }
            }
        }
    }

    // ---- block reduce (pos_local, haspos_local): wave shfl + LDS across 4 waves
    float a = pos_local, b = haspos_local;
    #pragma unroll
    for (int off = 32; off > 0; off >>= 1) {
        a += __shfl_down(a, off, 64);
        b += __shfl_down(b, off, 64);   // at most one nonzero lane overall
    }
    __shared__ float red_a[4], red_b[4];
    const int wave = t >> 6;
    const int lane = t & 63;
    if (lane == 0) { red_a[wave] = a; red_b[wave] = b; }
    __syncthreads();
    const float pos_score = red_a[0] + red_a[1] + red_a[2] + red_a[3];
    const float has_pos   = red_b[0] + red_b[1] + red_b[2] + red_b[3];

    const float chosen = (has_pos > 0.f) ? pos_score : -MARGIN;

    // ---- phase 2: hinge over negative valid elements (from registers)
    float hsum = 0.f, hcnt = 0.f;
    #pragma unroll
    for (int i = 0; i < 8; ++i) {
        if (negmask & (1u << i)) {
            hsum += fmaxf(MARGIN + sc[i] - chosen, 0.f);
            hcnt += 1.f;
        }
    }
    #pragma unroll
    for (int off = 32; off > 0; off >>= 1) {
        hsum += __shfl_down(hsum, off, 64);
        hcnt += __shfl_down(hcnt, off, 64);
    }
    __shared__ float red_h[4], red_c[4];
    if (lane == 0) { red_h[wave] = hsum; red_c[wave] = hcnt; }
    __syncthreads();
    if (t == 0) {
        const float H = red_h[0] + red_h[1] + red_h[2] + red_h[3];
        const float C = red_c[0] + red_c[1] + red_c[2] + red_c[3];
        if (C > 0.f) {   // valid_obs: len>0 (already known) && has_neg
            atomicAdd(&acc_sum[row & (NBUCKET - 1)], H / C);
            atomicAdd(&acc_cnt[row & (NBUCKET - 1)], 1.f);
        }
    }
}

__global__ __launch_bounds__(1024) void finalize_kernel(
    const float* __restrict__ acc_sum,
    const float* __restrict__ acc_cnt,
    float* __restrict__ out)
{
    const int t = threadIdx.x;
    float s = acc_sum[t];
    float c = acc_cnt[t];
    #pragma unroll
    for (int off = 32; off > 0; off >>= 1) {
        s += __shfl_down(s, off, 64);
        c += __shfl_down(c, off, 64);
    }
    __shared__ float sh_s[16], sh_c[16];
    const int wave = t >> 6, lane = t & 63;
    if (lane == 0) { sh_s[wave] = s; sh_c[wave] = c; }
    __syncthreads();
    if (t == 0) {
        float S = 0.f, C = 0.f;
        #pragma unroll
        for (int i = 0; i < 16; ++i) { S += sh_s[i]; C += sh_c[i]; }
        out[0] = (C > 0.f) ? (S / C) : 0.f;
    }
}

extern "C" void kernel_launch(void* const* d_in, const int* in_sizes, int n_in,
                              void* d_out, int out_size, void* d_ws, size_t ws_size,
                              hipStream_t stream) {
    const float* scores = (const float*)d_in[0];
    const int*   lens   = (const int*)d_in[1];
    const int*   labels = (const int*)d_in[2];
    const int B = in_sizes[1];                 // candidate_lengths element count

    float* acc_sum = (float*)d_ws;
    float* acc_cnt = acc_sum + NBUCKET;

    // d_ws is re-poisoned 0xAA before every timed launch: zero our buckets.
    hipMemsetAsync(d_ws, 0, 2 * NBUCKET * sizeof(float), stream);

    hinge_row_kernel<<<B, 256, 0, stream>>>(scores, lens, labels, acc_sum, acc_cnt);
    finalize_kernel<<<1, NBUCKET, 0, stream>>>(acc_sum, acc_cnt, (float*)d_out);
}